// Round 6
// baseline (528.257 us; speedup 1.0000x reference)
//
#include <hip/hip_runtime.h>

#define EMBD 32
#define KN 10

__device__ __forceinline__ float bf2f(unsigned short u){
    union{unsigned int v; float f;}c; c.v = ((unsigned int)u) << 16; return c.f;
}
__device__ __forceinline__ unsigned short f2bf(float f){
    union{float f; unsigned int u;}c; c.f=f;
    unsigned int r = c.u + 0x7FFFu + ((c.u>>16)&1u);   // RNE
    return (unsigned short)(r>>16);
}

// streaming f32 -> bf16 for the gather tables (~96 MB traffic)
__global__ __launch_bounds__(256)
void cvt_bf16(const float4* __restrict__ in, ushort4* __restrict__ out, int n4){
    int i = blockIdx.x*256 + threadIdx.x;
    if (i < n4){
        float4 v = in[i];
        ushort4 o; o.x=f2bf(v.x); o.y=f2bf(v.y); o.z=f2bf(v.z); o.w=f2bf(v.w);
        out[i]=o;
    }
}

// Layer 1, 64 rows/block.
// Gather (R2-verified shape): half-wave per row, lane=dim, ushort loads ->
//   exactly one 64 B line per half-wave instruction (~10.8 cyc/line measured;
//   8-lines-per-inst shapes measured 2x slower — R4/R5 post-mortem).
// Indices staged in LDS (coalesced) to break the idx->gather chain.
// Self term streamed f32 in the compute phase.
__global__ __launch_bounds__(256, 8)
void sage_l1(const float* __restrict__ emb,            // f32 [N,32]
             const unsigned short* __restrict__ embb,  // bf16 [N,32]
             const float* __restrict__ W,              // f32 [32][64]
             const int* __restrict__ neigh,            // [N,10]
             unsigned short* __restrict__ h1,          // bf16 out [N,32]
             int n_rows)
{
    __shared__ __align__(16) int sidx[64*KN];          // 2.5 KB
    __shared__ float sagg[64][33];                     // 8.25 KB
    const int tid  = threadIdx.x;
    const int row0 = blockIdx.x << 6;

    if (row0 + 64 <= n_rows) {                         // contiguous 2.5 KB of neigh
        if (tid < 160)
            ((int4*)sidx)[tid] = ((const int4*)(neigh + (size_t)row0*KN))[tid];
    } else {                                           // tail: OOB rows -> node 0
        for (int t = tid; t < 64*KN; t += 256) {
            int lr = t / KN;
            sidx[t] = (row0 + lr < n_rows) ? neigh[(size_t)row0*KN + t] : 0;
        }
    }
    __syncthreads();

    const int hw = tid >> 5;          // half-wave 0..7
    const int j  = tid & 31;          // feature dim
    #pragma unroll 2
    for (int i = 0; i < 8; ++i) {
        const int row = hw * 8 + i;
        float agg = 0.f;
        #pragma unroll
        for (int k = 0; k < KN; ++k) {
            const int idx = sidx[row*KN + k];          // LDS broadcast in half-wave
            agg += bf2f(embb[(size_t)idx*EMBD + j]);   // one 64 B line / half-wave
        }
        sagg[row][j] = agg * 0.1f;                     // 32 consecutive words: no conflict
    }
    __syncthreads();

    // compute: lane = row, wave wv -> outputs [8wv, 8wv+8)
    const int lane = tid & 63;
    const int wv   = tid >> 6;
    const int row  = lane;
    const int r    = row0 + row;
    const int rc   = (r < n_rows) ? r : (n_rows - 1);
    const float* selfrow = emb + (size_t)rc * EMBD;    // f32 coalesced stream
    const float* Wb = W + wv*8*64;                     // wave-uniform -> s_load

    float acc[8] = {0,0,0,0,0,0,0,0};
    #pragma unroll
    for (int c4 = 0; c4 < 8; ++c4) {                   // self half (dims 0..31)
        const float4 s = ((const float4*)selfrow)[c4];
        #pragma unroll
        for (int q = 0; q < 8; ++q) {
            acc[q] = fmaf(s.x, Wb[q*64 + c4*4 + 0], acc[q]);
            acc[q] = fmaf(s.y, Wb[q*64 + c4*4 + 1], acc[q]);
            acc[q] = fmaf(s.z, Wb[q*64 + c4*4 + 2], acc[q]);
            acc[q] = fmaf(s.w, Wb[q*64 + c4*4 + 3], acc[q]);
        }
    }
    #pragma unroll 8
    for (int jj = 0; jj < 32; ++jj) {                  // agg half (dims 32..63)
        const float c = sagg[row][jj];                 // (row+jj)%32: 2-way = free
        #pragma unroll
        for (int q = 0; q < 8; ++q)
            acc[q] = fmaf(c, Wb[q*64 + 32 + jj], acc[q]);
    }
    if (r < n_rows) {
        unsigned int pk[4];
        #pragma unroll
        for (int q = 0; q < 4; ++q) {
            float x0 = fmaxf(acc[2*q],0.f), x1 = fmaxf(acc[2*q+1],0.f);
            pk[q] = (unsigned int)f2bf(x0) | ((unsigned int)f2bf(x1)<<16);
        }
        *(uint4*)(h1 + (size_t)r*EMBD + wv*8) = make_uint4(pk[0],pk[1],pk[2],pk[3]);
    }
}

// Layer 2: batch + neighbor indices fully staged to LDS (breaks the
// batch->neigh->gather latency chain), then R2-shape gathers from h1.
__global__ __launch_bounds__(256, 8)
void sage_l2(const unsigned short* __restrict__ h1,   // bf16 [N,32]
             const float* __restrict__ W,             // f32 [32][64]
             const int* __restrict__ neigh,           // [N,10]
             const int* __restrict__ batch,           // [B]
             float* __restrict__ out,                 // f32 [B,32]
             int n_rows)
{
    __shared__ int snode[64];
    __shared__ __align__(16) int sidx[64*KN];
    __shared__ float sh[64][67];                      // [row][dim 0..63]
    const int tid  = threadIdx.x;
    const int row0 = blockIdx.x << 6;

    if (tid < 64) {
        int r = row0 + tid;
        snode[tid] = (r < n_rows) ? batch[r] : 0;     // coalesced, 1 inst
    }
    __syncthreads();
    for (int t = tid; t < 64*KN; t += 256) {          // 640 idx, coalesced-ish
        int lr = t / KN;
        int k  = t - lr*KN;
        sidx[t] = neigh[(size_t)snode[lr]*KN + k];
    }
    __syncthreads();

    const int hw = tid >> 5;
    const int j  = tid & 31;
    #pragma unroll 2
    for (int i = 0; i < 8; ++i) {
        const int row  = hw * 8 + i;
        const int node = snode[row];
        sh[row][j] = bf2f(h1[(size_t)node*EMBD + j]); // self: 1 line / half-wave
        float agg = 0.f;
        #pragma unroll
        for (int k = 0; k < KN; ++k) {
            const int idx = sidx[row*KN + k];
            agg += bf2f(h1[(size_t)idx*EMBD + j]);    // 1 line / half-wave
        }
        sh[row][32 + j] = agg * 0.1f;
    }
    __syncthreads();

    const int lane = tid & 63;
    const int wv   = tid >> 6;
    const int row  = lane;
    const int r    = row0 + row;
    const float* Wb = W + wv*8*64;                    // wave-uniform
    float acc[8] = {0,0,0,0,0,0,0,0};
    #pragma unroll 8
    for (int jj = 0; jj < 64; ++jj) {
        const float c = sh[row][jj];                  // (3row+jj)%32: 2-way = free
        #pragma unroll
        for (int q = 0; q < 8; ++q)
            acc[q] = fmaf(c, Wb[q*64 + jj], acc[q]);
    }
    if (r < n_rows) {
        float* dst = out + (size_t)r*EMBD + wv*8;
        ((float4*)dst)[0] = make_float4(fmaxf(acc[0],0.f),fmaxf(acc[1],0.f),
                                        fmaxf(acc[2],0.f),fmaxf(acc[3],0.f));
        ((float4*)dst)[1] = make_float4(fmaxf(acc[4],0.f),fmaxf(acc[5],0.f),
                                        fmaxf(acc[6],0.f),fmaxf(acc[7],0.f));
    }
}

extern "C" void kernel_launch(void* const* d_in, const int* in_sizes, int n_in,
                              void* d_out, int out_size, void* d_ws, size_t ws_size,
                              hipStream_t stream)
{
    // dict order: emb [N,32] f32, W1 [32,64] f32, W2 [32,64] f32,
    //             node_batch [B] i32, neigh [N,10] i32
    const float* emb        = (const float*)d_in[0];
    const float* W1         = (const float*)d_in[1];
    const float* W2         = (const float*)d_in[2];
    const int*   node_batch = (const int*)  d_in[3];
    const int*   neigh      = (const int*)  d_in[4];

    const int N = in_sizes[0] / EMBD;   // 500000
    const int B = in_sizes[3];          // 100000

    unsigned short* emb_bf = (unsigned short*)d_ws;              // 32 MB
    unsigned short* h1_bf  = emb_bf + (size_t)N * EMBD;          // 32 MB

    const int n4 = (N * EMBD) / 4;
    cvt_bf16<<<(n4 + 255) / 256, 256, 0, stream>>>(
        (const float4*)emb, (ushort4*)emb_bf, n4);

    sage_l1<<<(N + 63) / 64, 256, 0, stream>>>(
        emb, emb_bf, W1, neigh, h1_bf, N);

    sage_l2<<<(B + 63) / 64, 256, 0, stream>>>(
        h1_bf, W2, neigh, node_batch, (float*)d_out, B);
}

// Round 7
// 342.817 us; speedup vs baseline: 1.5409x; 1.5409x over previous
//
#include <hip/hip_runtime.h>

#define EMBD 32
#define KN 10

__device__ __forceinline__ float bf2f(unsigned short u){
    union{unsigned int v; float f;}c; c.v = ((unsigned int)u) << 16; return c.f;
}
__device__ __forceinline__ unsigned short f2bf(float f){
    union{float f; unsigned int u;}c; c.f=f;
    unsigned int r = c.u + 0x7FFFu + ((c.u>>16)&1u);   // RNE
    return (unsigned short)(r>>16);
}

// streaming f32 -> bf16 for the gather tables (~96 MB traffic)
__global__ __launch_bounds__(256)
void cvt_bf16(const float4* __restrict__ in, ushort4* __restrict__ out, int n4){
    int i = blockIdx.x*256 + threadIdx.x;
    if (i < n4){
        float4 v = in[i];
        ushort4 o; o.x=f2bf(v.x); o.y=f2bf(v.y); o.z=f2bf(v.z); o.w=f2bf(v.w);
        out[i]=o;
    }
}

// Layer 1, 64 rows/block. R2-verified gather (half-wave per row, lane=dim,
// ushort loads: one 64 B line per half-wave inst), LDS-staged indices.
// Output goes through an LDS transpose so every global store instruction
// covers FULL 64 B lines (R6 post-mortem: 4-wave partial-line stores under
// gather thrash caused 10x write amplification, 336 MB for 32 MB of data).
__global__ __launch_bounds__(256, 6)
void sage_l1(const unsigned short* __restrict__ embb,  // bf16 [N,32]
             const float* __restrict__ W,              // f32 [32][64]
             const int* __restrict__ neigh,            // [N,10]
             unsigned short* __restrict__ h1,          // bf16 out [N,32]
             int n_rows)
{
    __shared__ __align__(16) int sidx[64*KN];          // 2.5 KB
    __shared__ float sh[64][65];                       // 16.25 KB [row][dim 0..63]
    __shared__ unsigned int sout[64][17];              // 4.25 KB packed bf16 rows
    const int tid  = threadIdx.x;
    const int row0 = blockIdx.x << 6;

    if (row0 + 64 <= n_rows) {                         // contiguous 2.5 KB of neigh
        if (tid < 160)
            ((int4*)sidx)[tid] = ((const int4*)(neigh + (size_t)row0*KN))[tid];
    } else {                                           // tail: OOB rows -> node 0
        for (int t = tid; t < 64*KN; t += 256) {
            int lr = t / KN;
            sidx[t] = (row0 + lr < n_rows) ? neigh[(size_t)row0*KN + t] : 0;
        }
    }
    __syncthreads();

    const int hw = tid >> 5;          // half-wave 0..7
    const int j  = tid & 31;          // feature dim
    #pragma unroll 2
    for (int i = 0; i < 8; ++i) {
        const int row = hw * 8 + i;
        int rr = row0 + row; if (rr >= n_rows) rr = n_rows - 1;
        sh[row][j] = bf2f(embb[(size_t)rr*EMBD + j]);  // consecutive rows: coalesced
        float agg = 0.f;
        #pragma unroll
        for (int k = 0; k < KN; ++k) {
            const int idx = sidx[row*KN + k];          // LDS broadcast in half-wave
            agg += bf2f(embb[(size_t)idx*EMBD + j]);   // one 64 B line / half-wave
        }
        sh[row][32 + j] = agg * 0.1f;
    }
    __syncthreads();

    // compute: lane = row, wave wv -> output dims [8wv, 8wv+8)
    const int lane = tid & 63;
    const int wv   = tid >> 6;
    const float* Wb = W + wv*8*64;                     // wave-uniform -> s_load
    float acc[8] = {0,0,0,0,0,0,0,0};
    #pragma unroll 8
    for (int jj = 0; jj < 64; ++jj) {
        const float c = sh[lane][jj];                  // 2-way aliasing = free
        #pragma unroll
        for (int q = 0; q < 8; ++q)
            acc[q] = fmaf(c, Wb[q*64 + jj], acc[q]);
    }
    // pack relu(acc) -> quarter wv of row lane in LDS
    #pragma unroll
    for (int c = 0; c < 4; ++c) {
        float x0 = fmaxf(acc[2*c],0.f), x1 = fmaxf(acc[2*c+1],0.f);
        sout[lane][wv*4 + c] = (unsigned int)f2bf(x0) | ((unsigned int)f2bf(x1)<<16);
    }
    __syncthreads();

    // coalesced full-line store: thread t -> (row t>>2, 16 B quarter t&3);
    // one wave covers 16 complete consecutive 64 B rows.
    const int srow = tid >> 2, sq = tid & 3;
    if (row0 + srow < n_rows) {
        uint4 v = make_uint4(sout[srow][sq*4+0], sout[srow][sq*4+1],
                             sout[srow][sq*4+2], sout[srow][sq*4+3]);
        *(uint4*)(h1 + (size_t)(row0+srow)*EMBD + sq*8) = v;
    }
}

// Layer 2: batch + neighbor indices fully staged to LDS (chain break), R2-shape
// gathers from h1, and the same full-line store epilogue for the f32 output.
__global__ __launch_bounds__(256, 4)
void sage_l2(const unsigned short* __restrict__ h1,   // bf16 [N,32]
             const float* __restrict__ W,             // f32 [32][64]
             const int* __restrict__ neigh,           // [N,10]
             const int* __restrict__ batch,           // [B]
             float* __restrict__ out,                 // f32 [B,32]
             int n_rows)
{
    __shared__ int snode[64];
    __shared__ __align__(16) int sidx[64*KN];         // 2.5 KB
    __shared__ float sh[64][67];                      // 17.2 KB [row][dim 0..63]
    __shared__ float soutf[64][33];                   // 8.4 KB f32 rows
    const int tid  = threadIdx.x;
    const int row0 = blockIdx.x << 6;

    if (tid < 64) {
        int r = row0 + tid;
        snode[tid] = (r < n_rows) ? batch[r] : 0;     // coalesced, 1 inst
    }
    __syncthreads();
    for (int t = tid; t < 64*KN; t += 256) {          // 640 idx
        int lr = t / KN;
        int k  = t - lr*KN;
        sidx[t] = neigh[(size_t)snode[lr]*KN + k];
    }
    __syncthreads();

    const int hw = tid >> 5;
    const int j  = tid & 31;
    #pragma unroll 2
    for (int i = 0; i < 8; ++i) {
        const int row  = hw * 8 + i;
        const int node = snode[row];
        sh[row][j] = bf2f(h1[(size_t)node*EMBD + j]); // self: 1 line / half-wave
        float agg = 0.f;
        #pragma unroll
        for (int k = 0; k < KN; ++k) {
            const int idx = sidx[row*KN + k];
            agg += bf2f(h1[(size_t)idx*EMBD + j]);    // 1 line / half-wave
        }
        sh[row][32 + j] = agg * 0.1f;
    }
    __syncthreads();

    const int lane = tid & 63;
    const int wv   = tid >> 6;
    const float* Wb = W + wv*8*64;                    // wave-uniform
    float acc[8] = {0,0,0,0,0,0,0,0};
    #pragma unroll 8
    for (int jj = 0; jj < 64; ++jj) {
        const float c = sh[lane][jj];
        #pragma unroll
        for (int q = 0; q < 8; ++q)
            acc[q] = fmaf(c, Wb[q*64 + jj], acc[q]);
    }
    #pragma unroll
    for (int q = 0; q < 8; ++q)
        soutf[lane][wv*8 + q] = fmaxf(acc[q], 0.f);
    __syncthreads();

    // full-line f32 store: thread t -> (row t>>2, 16 B chunk), 2 passes cover
    // the 128 B row; every 64 B line fully written within one instruction.
    const int srow = tid >> 2, sc = tid & 3;
    if (row0 + srow < n_rows) {
        float* dst = out + (size_t)(row0+srow)*EMBD;
        #pragma unroll
        for (int p = 0; p < 2; ++p) {
            const int c0 = (p*4 + sc)*4;              // float offset in row
            float4 v = make_float4(soutf[srow][c0+0], soutf[srow][c0+1],
                                   soutf[srow][c0+2], soutf[srow][c0+3]);
            *(float4*)(dst + c0) = v;
        }
    }
}

extern "C" void kernel_launch(void* const* d_in, const int* in_sizes, int n_in,
                              void* d_out, int out_size, void* d_ws, size_t ws_size,
                              hipStream_t stream)
{
    // dict order: emb [N,32] f32, W1 [32,64] f32, W2 [32,64] f32,
    //             node_batch [B] i32, neigh [N,10] i32
    const float* emb        = (const float*)d_in[0];
    const float* W1         = (const float*)d_in[1];
    const float* W2         = (const float*)d_in[2];
    const int*   node_batch = (const int*)  d_in[3];
    const int*   neigh      = (const int*)  d_in[4];

    const int N = in_sizes[0] / EMBD;   // 500000
    const int B = in_sizes[3];          // 100000

    unsigned short* emb_bf = (unsigned short*)d_ws;              // 32 MB
    unsigned short* h1_bf  = emb_bf + (size_t)N * EMBD;          // 32 MB

    const int n4 = (N * EMBD) / 4;
    cvt_bf16<<<(n4 + 255) / 256, 256, 0, stream>>>(
        (const float4*)emb, (ushort4*)emb_bf, n4);

    sage_l1<<<(N + 63) / 64, 256, 0, stream>>>(
        emb_bf, W1, neigh, h1_bf, N);

    sage_l2<<<(B + 63) / 64, 256, 0, stream>>>(
        h1_bf, W2, neigh, node_batch, (float*)d_out, B);
}